// Round 1
// baseline (1371.076 us; speedup 1.0000x reference)
//
#include <hip/hip_runtime.h>

// ---------------------------------------------------------------------------
// Transformer_16784732193201 — round 1 baseline
// B=1024 T=81 D=256 H=8 M=3 DFF=512 J=17, 3 layers, fp32 in/out.
// Residual stream kept fp32 in ws; GEMM inputs bf16; MFMA 16x16x32 bf16.
// ws layout:
//   xbuf  fp32 [82944,256]               @ 0          (84,934,656 B)
//   bufA  bf16 [82944,256]               @ 84934656   (42,467,328 B)  LN out / attn O / xn
//   bufB  bf16 [82944,768]               @ 127401984  (127,401,984 B) qkv / ffn hidden
//   weights bf16                         @ 254803968  (~3.2 MB)
// ---------------------------------------------------------------------------

typedef __attribute__((ext_vector_type(4))) float f32x4;
typedef __attribute__((ext_vector_type(8))) short s16x8;
typedef __attribute__((ext_vector_type(4))) unsigned short u16x4;
typedef __attribute__((ext_vector_type(8))) unsigned short u16x8;

__device__ __forceinline__ float bf2f(unsigned short u) {
  unsigned int v = ((unsigned int)u) << 16;
  return __builtin_bit_cast(float, v);
}
__device__ __forceinline__ unsigned short f2bf(float f) {
  unsigned int u = __builtin_bit_cast(unsigned int, f);
  u += 0x7fffu + ((u >> 16) & 1u);
  return (unsigned short)(u >> 16);
}

#define GLD16(gp, lp)                                                       \
  __builtin_amdgcn_global_load_lds(                                         \
      (const __attribute__((address_space(1))) void*)(gp),                  \
      (__attribute__((address_space(3))) void*)(lp), 16, 0, 0)

// ---------------------------------------------------------------------------
// Generic bf16 GEMM:  C[m,n] = sum_k A[m,k] * W[n,k]  (+bias, epilogue)
// EPI: 0 = bias -> bf16 ; 1 = bias+relu -> bf16 ; 2 = bias+residual -> f32 ;
//      3 = bias -> f32
// BM=128, BK=64, 4 waves as 2x2, each wave 64 x (BN/2).
// ---------------------------------------------------------------------------
template <int BN, int EPI>
__global__ __launch_bounds__(256) void gemm_bt(
    const unsigned short* __restrict__ A, const unsigned short* __restrict__ W,
    const float* __restrict__ bias, const float* __restrict__ resid,
    void* __restrict__ Cout, int K, int ldc, int n_valid, int nW) {
  constexpr int BM = 128, BK = 64;
  constexpr int WN = BN / 2;
  constexpr int FM = 4, FN = WN / 16;
  __shared__ unsigned short Alds[BM * BK];
  __shared__ unsigned short Blds[BN * BK];

  const int tid = threadIdx.x, wave = tid >> 6, lane = tid & 63;
  const int row0 = blockIdx.x * BM, ncol0 = blockIdx.y * BN;
  const int wr = wave >> 1, wc = wave & 1;
  const int fr = lane & 15, ko = (lane >> 4) * 8;
  const int l8 = lane >> 3, lk = (lane & 7) * 8;

  f32x4 acc[FM][FN];
#pragma unroll
  for (int i = 0; i < FM; ++i)
#pragma unroll
    for (int j = 0; j < FN; ++j) acc[i][j] = (f32x4)0.f;

  const int nkt = K / BK;
  for (int kt = 0; kt < nkt; ++kt) {
    __syncthreads();
    // stage A tile [128][64]
#pragma unroll
    for (int j = 0; j < 4; ++j) {
      int ci = wave * 4 + j;
      int arow = row0 + ci * 8 + l8;
      const unsigned short* src = A + (size_t)arow * K + kt * BK + lk;
      GLD16(src, &Alds[ci * 512]);
    }
    // stage B tile [BN][64] (clamped rows for the 51-wide conv)
#pragma unroll
    for (int j = 0; j < BN / 32; ++j) {
      int ci = wave * (BN / 32) + j;
      int brow = ncol0 + ci * 8 + l8;
      if (brow >= nW) brow = nW - 1;
      const unsigned short* src = W + (size_t)brow * K + kt * BK + lk;
      GLD16(src, &Blds[ci * 512]);
    }
    __syncthreads();
#pragma unroll
    for (int kk = 0; kk < 2; ++kk) {
      s16x8 af[FM], bfr[FN];
#pragma unroll
      for (int i = 0; i < FM; ++i)
        af[i] = *(const s16x8*)&Alds[(wr * 64 + i * 16 + fr) * BK + kk * 32 + ko];
#pragma unroll
      for (int j = 0; j < FN; ++j)
        bfr[j] = *(const s16x8*)&Blds[(wc * WN + j * 16 + fr) * BK + kk * 32 + ko];
#pragma unroll
      for (int i = 0; i < FM; ++i)
#pragma unroll
        for (int j = 0; j < FN; ++j)
          acc[i][j] =
              __builtin_amdgcn_mfma_f32_16x16x32_bf16(af[i], bfr[j], acc[i][j], 0, 0, 0);
    }
  }

  // epilogue: D mapping col=lane&15, row=(lane>>4)*4+r
  const int cr = (lane >> 4) * 4, cc = lane & 15;
#pragma unroll
  for (int i = 0; i < FM; ++i) {
#pragma unroll
    for (int j = 0; j < FN; ++j) {
      int col = ncol0 + wc * WN + j * 16 + cc;
      if (col >= n_valid) continue;
      float bv = bias[col];
#pragma unroll
      for (int r = 0; r < 4; ++r) {
        int row = row0 + wr * 64 + i * 16 + cr + r;
        float v = acc[i][j][r] + bv;
        if constexpr (EPI == 1) v = fmaxf(v, 0.f);
        size_t idx = (size_t)row * ldc + col;
        if constexpr (EPI == 2) {
          ((float*)Cout)[idx] = v + resid[idx];
        } else if constexpr (EPI == 3) {
          ((float*)Cout)[idx] = v;
        } else {
          ((unsigned short*)Cout)[idx] = f2bf(v);
        }
      }
    }
  }
}

// ---------------------------------------------------------------------------
// LayerNorm: unbiased var (D-1), out = a*(x-mean)/(sqrt(var)+1e-6)+b -> bf16
// 1 wave per row (64 lanes x 4 floats), 4 rows per block.
// ---------------------------------------------------------------------------
__global__ __launch_bounds__(256) void ln_kernel(const float* __restrict__ x,
                                                 const float* __restrict__ a,
                                                 const float* __restrict__ b,
                                                 unsigned short* __restrict__ out) {
  const int wave = threadIdx.x >> 6, lane = threadIdx.x & 63;
  const size_t row = (size_t)blockIdx.x * 4 + wave;
  const float* xr = x + row * 256;
  f32x4 v = *(const f32x4*)(xr + lane * 4);
  float s = v[0] + v[1] + v[2] + v[3];
#pragma unroll
  for (int off = 32; off >= 1; off >>= 1) s += __shfl_xor(s, off);
  float mean = s * (1.f / 256.f);
  f32x4 d = v - mean;
  float sq = d[0] * d[0] + d[1] * d[1] + d[2] * d[2] + d[3] * d[3];
#pragma unroll
  for (int off = 32; off >= 1; off >>= 1) sq += __shfl_xor(sq, off);
  float var = sq * (1.f / 255.f);
  float scl = 1.f / (sqrtf(var) + 1e-6f);
  f32x4 av = *(const f32x4*)(a + lane * 4);
  f32x4 bv = *(const f32x4*)(b + lane * 4);
  u16x4 ob;
#pragma unroll
  for (int j = 0; j < 4; ++j) ob[j] = f2bf(av[j] * d[j] * scl + bv[j]);
  *(u16x4*)(out + row * 256 + lane * 4) = ob;
}

// ---------------------------------------------------------------------------
// Strided sparse attention: stream (b,h,m) over positions t = m + 3g, g<27.
// 1 wave per stream, 4 streams/block. K,V staged fp32 in LDS; per-lane row.
// ---------------------------------------------------------------------------
__global__ __launch_bounds__(256) void attn_kernel(const unsigned short* __restrict__ qkv,
                                                   unsigned short* __restrict__ o) {
  const int wave = threadIdx.x >> 6, lane = threadIdx.x & 63;
  const int sid = blockIdx.x * 4 + wave;
  const int m = sid % 3, hh = (sid / 3) & 7, b = sid / 24;
  __shared__ float KV[4][2][27 * 32];
  float* Kl = KV[wave][0];
  float* Vl = KV[wave][1];
  const unsigned short* base = qkv + (size_t)b * 81 * 768 + (size_t)m * 768 + hh * 32;
  for (int i = lane; i < 864; i += 64) {
    int g = i >> 5, d = i & 31;
    size_t off = (size_t)g * 3 * 768 + d;
    Kl[i] = bf2f(base[256 + off]);
    Vl[i] = bf2f(base[512 + off]);
  }
  __syncthreads();
  const int gq = (lane < 27) ? lane : 26;
  const unsigned short* qp = base + (size_t)gq * 2304;
  float q[32];
#pragma unroll
  for (int d4 = 0; d4 < 4; ++d4) {
    u16x8 u = *(const u16x8*)(qp + d4 * 8);
#pragma unroll
    for (int j = 0; j < 8; ++j) q[d4 * 8 + j] = bf2f(u[j]);
  }
  float sc[27];
#pragma unroll
  for (int kk = 0; kk < 27; ++kk) {
    float s = 0.f;
#pragma unroll
    for (int d = 0; d < 32; ++d) s += q[d] * Kl[kk * 32 + d];
    sc[kk] = s * 0.17677669529663687f;  // 1/sqrt(32)
  }
  float mx = sc[0];
#pragma unroll
  for (int kk = 1; kk < 27; ++kk) mx = fmaxf(mx, sc[kk]);
  float sum = 0.f;
#pragma unroll
  for (int kk = 0; kk < 27; ++kk) {
    sc[kk] = __expf(sc[kk] - mx);
    sum += sc[kk];
  }
  float inv = 1.f / sum;
  float ov[32];
#pragma unroll
  for (int d = 0; d < 32; ++d) ov[d] = 0.f;
#pragma unroll
  for (int kk = 0; kk < 27; ++kk) {
    float p = sc[kk] * inv;
#pragma unroll
    for (int d = 0; d < 32; ++d) ov[d] += p * Vl[kk * 32 + d];
  }
  if (lane < 27) {
    unsigned short* op = o + (size_t)(b * 81 + m + 3 * gq) * 256 + hh * 32;
#pragma unroll
    for (int d4 = 0; d4 < 4; ++d4) {
      u16x8 u;
#pragma unroll
      for (int j = 0; j < 8; ++j) u[j] = f2bf(ov[d4 * 8 + j]);
      *(u16x8*)(op + d4 * 8) = u;
    }
  }
}

// x + pos_emb (pos broadcast over batch), float4 per thread
__global__ __launch_bounds__(256) void addpos_kernel(const f32x4* __restrict__ x,
                                                     const f32x4* __restrict__ pos,
                                                     f32x4* __restrict__ out) {
  int i = blockIdx.x * 256 + threadIdx.x;  // 5,308,416 float4s
  out[i] = x[i] + pos[i % 5184];
}

// eval BatchNorm (mean0/var1) fused cast: xn = x/sqrt(1+1e-5)*g + b -> bf16
__global__ __launch_bounds__(256) void bn_kernel(const float* __restrict__ x,
                                                 const float* __restrict__ g,
                                                 const float* __restrict__ bb,
                                                 unsigned short* __restrict__ out) {
  int i = blockIdx.x * 256 + threadIdx.x;  // float4 index
  f32x4 v = ((const f32x4*)x)[i];
  int c = (i << 2) & 255;
  f32x4 gv = *(const f32x4*)(g + c);
  f32x4 bv = *(const f32x4*)(bb + c);
  const float is = 0.9999950000374997f;  // 1/sqrt(1.00001)
  u16x4 o;
#pragma unroll
  for (int j = 0; j < 4; ++j) o[j] = f2bf(v[j] * is * gv[j] + bv[j]);
  ((u16x4*)out)[i] = o;
}

__global__ __launch_bounds__(256) void cvt_kernel(const f32x4* __restrict__ src,
                                                  u16x4* __restrict__ dst, int n4) {
  int i = blockIdx.x * 256 + threadIdx.x;
  if (i < n4) {
    f32x4 v = src[i];
    u16x4 o;
#pragma unroll
    for (int j = 0; j < 4; ++j) o[j] = f2bf(v[j]);
    dst[i] = o;
  }
}

extern "C" void kernel_launch(void* const* d_in, const int* in_sizes, int n_in,
                              void* d_out, int out_size, void* d_ws, size_t ws_size,
                              hipStream_t stream) {
  const float* x      = (const float*)d_in[0];
  const float* pos    = (const float*)d_in[1];
  const float* ln1_a  = (const float*)d_in[2];
  const float* ln1_b  = (const float*)d_in[3];
  const float* Wq     = (const float*)d_in[4];
  const float* bq     = (const float*)d_in[5];
  const float* Wk     = (const float*)d_in[6];
  const float* bk     = (const float*)d_in[7];
  const float* Wv     = (const float*)d_in[8];
  const float* bv     = (const float*)d_in[9];
  const float* Wo     = (const float*)d_in[10];
  const float* bo     = (const float*)d_in[11];
  const float* ln2_a  = (const float*)d_in[12];
  const float* ln2_b  = (const float*)d_in[13];
  const float* W1     = (const float*)d_in[14];
  const float* b1     = (const float*)d_in[15];
  const float* W2     = (const float*)d_in[16];
  const float* b2     = (const float*)d_in[17];
  const float* bn_g   = (const float*)d_in[18];
  const float* bn_b   = (const float*)d_in[19];
  const float* conv_w = (const float*)d_in[20];
  const float* conv_b = (const float*)d_in[21];

  char* ws = (char*)d_ws;
  float* xbuf = (float*)ws;
  unsigned short* bufA = (unsigned short*)(ws + 84934656);
  unsigned short* bufB = (unsigned short*)(ws + 127401984);
  unsigned short* wq3 = (unsigned short*)(ws + 254803968);
  unsigned short* wk3 = wq3 + 196608;
  unsigned short* wv3 = wk3 + 196608;
  unsigned short* wo3 = wv3 + 196608;
  unsigned short* w13 = wo3 + 196608;
  unsigned short* w23 = w13 + 393216;
  unsigned short* cw  = w23 + 393216;

  auto cvt = [&](const float* s, unsigned short* d, int n) {
    int n4 = n / 4;
    cvt_kernel<<<(n4 + 255) / 256, 256, 0, stream>>>((const f32x4*)s, (u16x4*)d, n4);
  };
  cvt(Wq, wq3, 196608);
  cvt(Wk, wk3, 196608);
  cvt(Wv, wv3, 196608);
  cvt(Wo, wo3, 196608);
  cvt(W1, w13, 393216);
  cvt(W2, w23, 393216);
  cvt(conv_w, cw, 13056);

  addpos_kernel<<<20736, 256, 0, stream>>>((const f32x4*)x, (const f32x4*)pos, (f32x4*)xbuf);

  for (int l = 0; l < 3; ++l) {
    ln_kernel<<<20736, 256, 0, stream>>>(xbuf, ln1_a + l * 256, ln1_b + l * 256, bufA);
    // fused-layout QKV: three GEMMs into one [BT,768] buffer
    gemm_bt<128, 0><<<dim3(648, 2), 256, 0, stream>>>(bufA, wq3 + l * 65536, bq + l * 256,
                                                      nullptr, (void*)bufB, 256, 768, 256, 256);
    gemm_bt<128, 0><<<dim3(648, 2), 256, 0, stream>>>(bufA, wk3 + l * 65536, bk + l * 256,
                                                      nullptr, (void*)(bufB + 256), 256, 768, 256, 256);
    gemm_bt<128, 0><<<dim3(648, 2), 256, 0, stream>>>(bufA, wv3 + l * 65536, bv + l * 256,
                                                      nullptr, (void*)(bufB + 512), 256, 768, 256, 256);
    attn_kernel<<<6144, 256, 0, stream>>>(bufB, bufA);
    gemm_bt<128, 2><<<dim3(648, 2), 256, 0, stream>>>(bufA, wo3 + l * 65536, bo + l * 256,
                                                      xbuf, (void*)xbuf, 256, 256, 256, 256);
    ln_kernel<<<20736, 256, 0, stream>>>(xbuf, ln2_a + l * 256, ln2_b + l * 256, bufA);
    gemm_bt<128, 1><<<dim3(648, 4), 256, 0, stream>>>(bufA, w13 + l * 131072, b1 + l * 512,
                                                      nullptr, (void*)bufB, 256, 512, 512, 512);
    gemm_bt<128, 2><<<dim3(648, 2), 256, 0, stream>>>(bufB, w23 + l * 131072, b2 + l * 256,
                                                      xbuf, (void*)xbuf, 512, 256, 256, 256);
  }
  bn_kernel<<<20736, 256, 0, stream>>>(xbuf, bn_g, bn_b, bufA);
  gemm_bt<64, 3><<<dim3(648, 1), 256, 0, stream>>>(bufA, cw, conv_b, nullptr, d_out, 256, 51,
                                                   51, 51);
}

// Round 2
// 1103.037 us; speedup vs baseline: 1.2430x; 1.2430x over previous
//
#include <hip/hip_runtime.h>

// ---------------------------------------------------------------------------
// Transformer_16784732193201 — round 2
// B=1024 T=81 D=256 H=8 M=3 DFF=512 J=17, 3 layers, fp32 in/out.
// Changes vs r1: MFMA-based strided attention; fused QKV GEMM (1 launch).
// ws layout:
//   xbuf  fp32 [82944,256]               @ 0          (84,934,656 B)
//   bufA  bf16 [82944,256]               @ 84934656   (42,467,328 B)
//   bufB  bf16 [82944,768]               @ 127401984  (127,401,984 B)
//   weights bf16 + fused bias            @ 254803968  (~3.2 MB)
// ---------------------------------------------------------------------------

typedef __attribute__((ext_vector_type(4))) float f32x4;
typedef __attribute__((ext_vector_type(8))) short s16x8;
typedef __attribute__((ext_vector_type(4))) unsigned short u16x4;
typedef __attribute__((ext_vector_type(8))) unsigned short u16x8;

__device__ __forceinline__ float bf2f(unsigned short u) {
  unsigned int v = ((unsigned int)u) << 16;
  return __builtin_bit_cast(float, v);
}
__device__ __forceinline__ unsigned short f2bf(float f) {
  unsigned int u = __builtin_bit_cast(unsigned int, f);
  u += 0x7fffu + ((u >> 16) & 1u);
  return (unsigned short)(u >> 16);
}

#define GLD16(gp, lp)                                                       \
  __builtin_amdgcn_global_load_lds(                                         \
      (const __attribute__((address_space(1))) void*)(gp),                  \
      (__attribute__((address_space(3))) void*)(lp), 16, 0, 0)

// ---------------------------------------------------------------------------
// Generic bf16 GEMM:  C[m,n] = sum_k A[m,k] * W[n,k]  (+bias, epilogue)
// EPI: 0 = bias -> bf16 ; 1 = bias+relu -> bf16 ; 2 = bias+residual -> f32 ;
//      3 = bias -> f32
// BM=128, BK=64, 4 waves as 2x2, each wave 64 x (BN/2).
// ---------------------------------------------------------------------------
template <int BN, int EPI>
__global__ __launch_bounds__(256) void gemm_bt(
    const unsigned short* __restrict__ A, const unsigned short* __restrict__ W,
    const float* __restrict__ bias, const float* __restrict__ resid,
    void* __restrict__ Cout, int K, int ldc, int n_valid, int nW) {
  constexpr int BM = 128, BK = 64;
  constexpr int WN = BN / 2;
  constexpr int FM = 4, FN = WN / 16;
  __shared__ unsigned short Alds[BM * BK];
  __shared__ unsigned short Blds[BN * BK];

  const int tid = threadIdx.x, wave = tid >> 6, lane = tid & 63;
  const int row0 = blockIdx.x * BM, ncol0 = blockIdx.y * BN;
  const int wr = wave >> 1, wc = wave & 1;
  const int fr = lane & 15, ko = (lane >> 4) * 8;
  const int l8 = lane >> 3, lk = (lane & 7) * 8;

  f32x4 acc[FM][FN];
#pragma unroll
  for (int i = 0; i < FM; ++i)
#pragma unroll
    for (int j = 0; j < FN; ++j) acc[i][j] = (f32x4)0.f;

  const int nkt = K / BK;
  for (int kt = 0; kt < nkt; ++kt) {
    __syncthreads();
    // stage A tile [128][64]
#pragma unroll
    for (int j = 0; j < 4; ++j) {
      int ci = wave * 4 + j;
      int arow = row0 + ci * 8 + l8;
      const unsigned short* src = A + (size_t)arow * K + kt * BK + lk;
      GLD16(src, &Alds[ci * 512]);
    }
    // stage B tile [BN][64] (clamped rows for the 51-wide conv)
#pragma unroll
    for (int j = 0; j < BN / 32; ++j) {
      int ci = wave * (BN / 32) + j;
      int brow = ncol0 + ci * 8 + l8;
      if (brow >= nW) brow = nW - 1;
      const unsigned short* src = W + (size_t)brow * K + kt * BK + lk;
      GLD16(src, &Blds[ci * 512]);
    }
    __syncthreads();
#pragma unroll
    for (int kk = 0; kk < 2; ++kk) {
      s16x8 af[FM], bfr[FN];
#pragma unroll
      for (int i = 0; i < FM; ++i)
        af[i] = *(const s16x8*)&Alds[(wr * 64 + i * 16 + fr) * BK + kk * 32 + ko];
#pragma unroll
      for (int j = 0; j < FN; ++j)
        bfr[j] = *(const s16x8*)&Blds[(wc * WN + j * 16 + fr) * BK + kk * 32 + ko];
#pragma unroll
      for (int i = 0; i < FM; ++i)
#pragma unroll
        for (int j = 0; j < FN; ++j)
          acc[i][j] =
              __builtin_amdgcn_mfma_f32_16x16x32_bf16(af[i], bfr[j], acc[i][j], 0, 0, 0);
    }
  }

  // epilogue: D mapping col=lane&15, row=(lane>>4)*4+r
  const int cr = (lane >> 4) * 4, cc = lane & 15;
#pragma unroll
  for (int i = 0; i < FM; ++i) {
#pragma unroll
    for (int j = 0; j < FN; ++j) {
      int col = ncol0 + wc * WN + j * 16 + cc;
      if (col >= n_valid) continue;
      float bv = bias[col];
#pragma unroll
      for (int r = 0; r < 4; ++r) {
        int row = row0 + wr * 64 + i * 16 + cr + r;
        float v = acc[i][j][r] + bv;
        if constexpr (EPI == 1) v = fmaxf(v, 0.f);
        size_t idx = (size_t)row * ldc + col;
        if constexpr (EPI == 2) {
          ((float*)Cout)[idx] = v + resid[idx];
        } else if constexpr (EPI == 3) {
          ((float*)Cout)[idx] = v;
        } else {
          ((unsigned short*)Cout)[idx] = f2bf(v);
        }
      }
    }
  }
}

// ---------------------------------------------------------------------------
// LayerNorm: unbiased var (D-1), out = a*(x-mean)/(sqrt(var)+1e-6)+b -> bf16
// ---------------------------------------------------------------------------
__global__ __launch_bounds__(256) void ln_kernel(const float* __restrict__ x,
                                                 const float* __restrict__ a,
                                                 const float* __restrict__ b,
                                                 unsigned short* __restrict__ out) {
  const int wave = threadIdx.x >> 6, lane = threadIdx.x & 63;
  const size_t row = (size_t)blockIdx.x * 4 + wave;
  const float* xr = x + row * 256;
  f32x4 v = *(const f32x4*)(xr + lane * 4);
  float s = v[0] + v[1] + v[2] + v[3];
#pragma unroll
  for (int off = 32; off >= 1; off >>= 1) s += __shfl_xor(s, off);
  float mean = s * (1.f / 256.f);
  f32x4 d = v - mean;
  float sq = d[0] * d[0] + d[1] * d[1] + d[2] * d[2] + d[3] * d[3];
#pragma unroll
  for (int off = 32; off >= 1; off >>= 1) sq += __shfl_xor(sq, off);
  float var = sq * (1.f / 255.f);
  float scl = 1.f / (sqrtf(var) + 1e-6f);
  f32x4 av = *(const f32x4*)(a + lane * 4);
  f32x4 bv = *(const f32x4*)(b + lane * 4);
  u16x4 ob;
#pragma unroll
  for (int j = 0; j < 4; ++j) ob[j] = f2bf(av[j] * d[j] * scl + bv[j]);
  *(u16x4*)(out + row * 256 + lane * 4) = ob;
}

// ---------------------------------------------------------------------------
// MFMA strided sparse attention. 1 wave = 1 stream (b,h,m); 4 waves/block.
// Q,K frags loaded straight from global; V transposed into LDS; S=QK^T via
// 4 MFMAs; softmax in C-layout regs (16-lane shfl reduce); P->LDS bf16;
// PV via 4 MFMAs; O staged in LDS (reusing Vt) for coalesced stores.
// LDS row stride = 40 shorts (80 B): keeps ds_read_b128 16B-aligned and
// ~2-way banks.
// ---------------------------------------------------------------------------
__global__ __launch_bounds__(256) void attn_mfma(const unsigned short* __restrict__ qkv,
                                                 unsigned short* __restrict__ o) {
  constexpr int LS = 40;  // LDS row stride in shorts
  const int wave = threadIdx.x >> 6, lane = threadIdx.x & 63;
  const int sid = blockIdx.x * 4 + wave;
  const int m = sid % 3, hh = (sid / 3) & 7, b = sid / 24;
  __shared__ unsigned short VtS[4][32 * LS];
  __shared__ unsigned short PlS[4][32 * LS];
  unsigned short* vt = VtS[wave];
  unsigned short* pl = PlS[wave];

  const unsigned short* base = qkv + (size_t)b * 81 * 768 + (size_t)m * 768 + hh * 32;
  const int fr = lane & 15;        // fragment row index (q / kix / d)
  const int ko = (lane >> 4) * 8;  // k-dim slice start
  const int g4 = lane >> 4;

  // Q and K fragments from global (row-clamped; dup of row 26 is masked later)
  s16x8 qf[2], kf[2];
#pragma unroll
  for (int i = 0; i < 2; ++i) {
    int g = fr + 16 * i;
    if (g > 26) g = 26;
    const unsigned short* qp = base + (size_t)g * 2304 + ko;
    qf[i] = *(const s16x8*)qp;
    kf[i] = *(const s16x8*)(qp + 256);
  }

  // Stage V transposed: vt[d][k] = V[k][d], zero pad k>=27
#pragma unroll
  for (int it = 0; it < 2; ++it) {
    int slot = it * 64 + lane;
    int g = slot >> 2, s = slot & 3;
    if (g < 27) {
      u16x8 v = *(const u16x8*)(base + (size_t)g * 2304 + 512 + s * 8);
#pragma unroll
      for (int j = 0; j < 8; ++j) vt[(s * 8 + j) * LS + g] = v[j];
    } else {
#pragma unroll
      for (int j = 0; j < 8; ++j) vt[(s * 8 + j) * LS + g] = 0;
    }
  }

  // S = Q K^T (padded 32x32), quadrants [i][j]
  f32x4 sacc[2][2];
#pragma unroll
  for (int i = 0; i < 2; ++i)
#pragma unroll
    for (int j = 0; j < 2; ++j) sacc[i][j] = (f32x4)0.f;
#pragma unroll
  for (int i = 0; i < 2; ++i)
#pragma unroll
    for (int j = 0; j < 2; ++j)
      sacc[i][j] = __builtin_amdgcn_mfma_f32_16x16x32_bf16(qf[i], kf[j], sacc[i][j], 0, 0, 0);

  // softmax over k (cols): row = i*16+4*g4+r, col = j*16+fr; valid col<27
  const float scale = 0.17677669529663687f;  // 1/sqrt(32)
  const bool v1 = fr < 11;
#pragma unroll
  for (int i = 0; i < 2; ++i) {
#pragma unroll
    for (int r = 0; r < 4; ++r) {
      float a0 = sacc[i][0][r] * scale;
      float a1 = v1 ? sacc[i][1][r] * scale : -3.0e38f;
      float mx = fmaxf(a0, a1);
#pragma unroll
      for (int off = 1; off <= 8; off <<= 1) mx = fmaxf(mx, __shfl_xor(mx, off));
      float e0 = __expf(a0 - mx);
      float e1 = v1 ? __expf(a1 - mx) : 0.f;
      float sm = e0 + e1;
#pragma unroll
      for (int off = 1; off <= 8; off <<= 1) sm += __shfl_xor(sm, off);
      float inv = 1.f / sm;
      int row = i * 16 + 4 * g4 + r;
      pl[row * LS + fr] = f2bf(e0 * inv);
      pl[row * LS + 16 + fr] = f2bf(e1 * inv);
    }
  }
  __syncthreads();  // P + Vt visible

  // P A-frags and V^T B-frags
  s16x8 pf[2], vf[2];
#pragma unroll
  for (int i = 0; i < 2; ++i) pf[i] = *(const s16x8*)&pl[(fr + 16 * i) * LS + ko];
#pragma unroll
  for (int j = 0; j < 2; ++j) vf[j] = *(const s16x8*)&vt[(fr + 16 * j) * LS + ko];

  f32x4 oacc[2][2];
#pragma unroll
  for (int i = 0; i < 2; ++i)
#pragma unroll
    for (int j = 0; j < 2; ++j) oacc[i][j] = (f32x4)0.f;
#pragma unroll
  for (int i = 0; i < 2; ++i)
#pragma unroll
    for (int j = 0; j < 2; ++j)
      oacc[i][j] = __builtin_amdgcn_mfma_f32_16x16x32_bf16(pf[i], vf[j], oacc[i][j], 0, 0, 0);

  __syncthreads();  // vf/pf reads drained; safe to overwrite vt with O
#pragma unroll
  for (int i = 0; i < 2; ++i)
#pragma unroll
    for (int j = 0; j < 2; ++j)
#pragma unroll
      for (int r = 0; r < 4; ++r)
        vt[(i * 16 + 4 * g4 + r) * LS + j * 16 + fr] = f2bf(oacc[i][j][r]);
  __syncthreads();

  // coalesced store: row g (<27), 16B per lane
#pragma unroll
  for (int it = 0; it < 2; ++it) {
    int slot = it * 64 + lane;
    int g = slot >> 2, s = slot & 3;
    if (g < 27) {
      u16x8 v = *(const u16x8*)&vt[g * LS + s * 8];
      *(u16x8*)(o + (size_t)(b * 81 + m + 3 * g) * 256 + hh * 32 + s * 8) = v;
    }
  }
}

// x + pos_emb (pos broadcast over batch), float4 per thread
__global__ __launch_bounds__(256) void addpos_kernel(const f32x4* __restrict__ x,
                                                     const f32x4* __restrict__ pos,
                                                     f32x4* __restrict__ out) {
  int i = blockIdx.x * 256 + threadIdx.x;  // 5,308,416 float4s
  out[i] = x[i] + pos[i % 5184];
}

// eval BatchNorm (mean0/var1) fused cast: xn = x/sqrt(1+1e-5)*g + b -> bf16
__global__ __launch_bounds__(256) void bn_kernel(const float* __restrict__ x,
                                                 const float* __restrict__ g,
                                                 const float* __restrict__ bb,
                                                 unsigned short* __restrict__ out) {
  int i = blockIdx.x * 256 + threadIdx.x;  // float4 index
  f32x4 v = ((const f32x4*)x)[i];
  int c = (i << 2) & 255;
  f32x4 gv = *(const f32x4*)(g + c);
  f32x4 bv = *(const f32x4*)(bb + c);
  const float is = 0.9999950000374997f;  // 1/sqrt(1.00001)
  u16x4 o;
#pragma unroll
  for (int j = 0; j < 4; ++j) o[j] = f2bf(v[j] * is * gv[j] + bv[j]);
  ((u16x4*)out)[i] = o;
}

__global__ __launch_bounds__(256) void cvt_kernel(const f32x4* __restrict__ src,
                                                  u16x4* __restrict__ dst, int n4) {
  int i = blockIdx.x * 256 + threadIdx.x;
  if (i < n4) {
    f32x4 v = src[i];
    u16x4 o;
#pragma unroll
    for (int j = 0; j < 4; ++j) o[j] = f2bf(v[j]);
    dst[i] = o;
  }
}

// pack Wq|Wk|Wv -> wqkv3 bf16 [3][768][256]
__global__ __launch_bounds__(256) void qkvpack_kernel(const float* __restrict__ Wq,
                                                      const float* __restrict__ Wk,
                                                      const float* __restrict__ Wv,
                                                      u16x4* __restrict__ dst) {
  int i4 = blockIdx.x * 256 + threadIdx.x;  // 147456 total
  int e = i4 * 4;
  int l = e / 196608;
  int r = (e / 256) % 768;
  int c = e & 255;
  const float* src;
  if (r < 256) src = Wq + (size_t)l * 65536 + r * 256 + c;
  else if (r < 512) src = Wk + (size_t)l * 65536 + (r - 256) * 256 + c;
  else src = Wv + (size_t)l * 65536 + (r - 512) * 256 + c;
  f32x4 v = *(const f32x4*)src;
  u16x4 o;
#pragma unroll
  for (int j = 0; j < 4; ++j) o[j] = f2bf(v[j]);
  dst[i4] = o;
}

__global__ __launch_bounds__(256) void biaspack_kernel(const float* __restrict__ bq,
                                                       const float* __restrict__ bk,
                                                       const float* __restrict__ bv,
                                                       float* __restrict__ dst) {
  int i = blockIdx.x * 256 + threadIdx.x;
  if (i >= 2304) return;
  int l = i / 768, r = i % 768;
  float v = (r < 256) ? bq[l * 256 + r] : (r < 512) ? bk[l * 256 + r - 256]
                                                    : bv[l * 256 + r - 512];
  dst[i] = v;
}

extern "C" void kernel_launch(void* const* d_in, const int* in_sizes, int n_in,
                              void* d_out, int out_size, void* d_ws, size_t ws_size,
                              hipStream_t stream) {
  const float* x      = (const float*)d_in[0];
  const float* pos    = (const float*)d_in[1];
  const float* ln1_a  = (const float*)d_in[2];
  const float* ln1_b  = (const float*)d_in[3];
  const float* Wq     = (const float*)d_in[4];
  const float* bq     = (const float*)d_in[5];
  const float* Wk     = (const float*)d_in[6];
  const float* bk     = (const float*)d_in[7];
  const float* Wv     = (const float*)d_in[8];
  const float* bv     = (const float*)d_in[9];
  const float* Wo     = (const float*)d_in[10];
  const float* bo     = (const float*)d_in[11];
  const float* ln2_a  = (const float*)d_in[12];
  const float* ln2_b  = (const float*)d_in[13];
  const float* W1     = (const float*)d_in[14];
  const float* b1     = (const float*)d_in[15];
  const float* W2     = (const float*)d_in[16];
  const float* b2     = (const float*)d_in[17];
  const float* bn_g   = (const float*)d_in[18];
  const float* bn_b   = (const float*)d_in[19];
  const float* conv_w = (const float*)d_in[20];
  const float* conv_b = (const float*)d_in[21];

  char* ws = (char*)d_ws;
  float* xbuf = (float*)ws;
  unsigned short* bufA = (unsigned short*)(ws + 84934656);
  unsigned short* bufB = (unsigned short*)(ws + 127401984);
  unsigned short* wqkv3 = (unsigned short*)(ws + 254803968);
  unsigned short* wo3 = wqkv3 + 589824;
  unsigned short* w13 = wo3 + 196608;
  unsigned short* w23 = w13 + 393216;
  unsigned short* cw  = w23 + 393216;
  float* qkvb3 = (float*)(ws + 254803968 + 3171840);

  auto cvt = [&](const float* s, unsigned short* d, int n) {
    int n4 = n / 4;
    cvt_kernel<<<(n4 + 255) / 256, 256, 0, stream>>>((const f32x4*)s, (u16x4*)d, n4);
  };
  qkvpack_kernel<<<576, 256, 0, stream>>>(Wq, Wk, Wv, (u16x4*)wqkv3);
  biaspack_kernel<<<9, 256, 0, stream>>>(bq, bk, bv, qkvb3);
  cvt(Wo, wo3, 196608);
  cvt(W1, w13, 393216);
  cvt(W2, w23, 393216);
  cvt(conv_w, cw, 13056);

  addpos_kernel<<<20736, 256, 0, stream>>>((const f32x4*)x, (const f32x4*)pos, (f32x4*)xbuf);

  for (int l = 0; l < 3; ++l) {
    ln_kernel<<<20736, 256, 0, stream>>>(xbuf, ln1_a + l * 256, ln1_b + l * 256, bufA);
    // fused QKV: one GEMM into [BT,768]
    gemm_bt<128, 0><<<dim3(648, 6), 256, 0, stream>>>(bufA, wqkv3 + l * 196608,
                                                      qkvb3 + l * 768, nullptr,
                                                      (void*)bufB, 256, 768, 768, 768);
    attn_mfma<<<6144, 256, 0, stream>>>(bufB, bufA);
    gemm_bt<128, 2><<<dim3(648, 2), 256, 0, stream>>>(bufA, wo3 + l * 65536, bo + l * 256,
                                                      xbuf, (void*)xbuf, 256, 256, 256, 256);
    ln_kernel<<<20736, 256, 0, stream>>>(xbuf, ln2_a + l * 256, ln2_b + l * 256, bufA);
    gemm_bt<128, 1><<<dim3(648, 4), 256, 0, stream>>>(bufA, w13 + l * 131072, b1 + l * 512,
                                                      nullptr, (void*)bufB, 256, 512, 512, 512);
    gemm_bt<128, 2><<<dim3(648, 2), 256, 0, stream>>>(bufB, w23 + l * 131072, b2 + l * 256,
                                                      xbuf, (void*)xbuf, 512, 256, 256, 256);
  }
  bn_kernel<<<20736, 256, 0, stream>>>(xbuf, bn_g, bn_b, bufA);
  gemm_bt<64, 3><<<dim3(648, 1), 256, 0, stream>>>(bufA, cw, conv_b, nullptr, d_out, 256, 51,
                                                   51, 51);
}

// Round 3
// 934.073 us; speedup vs baseline: 1.4678x; 1.1809x over previous
//
#include <hip/hip_runtime.h>

// ---------------------------------------------------------------------------
// Transformer_16784732193201 — round 3
// Changes vs r2: GEMM T2 LDS XOR-swizzle (pre-swizzled global source, rule 21)
// + 1-D grid with bijective XCD swizzle and y-fastest order (A-panel L2 reuse).
// ws layout:
//   xbuf  fp32 [82944,256]               @ 0          (84,934,656 B)
//   bufA  bf16 [82944,256]               @ 84934656   (42,467,328 B)
//   bufB  bf16 [82944,768]               @ 127401984  (127,401,984 B)
//   weights bf16 + fused bias            @ 254803968  (~3.2 MB)
// ---------------------------------------------------------------------------

typedef __attribute__((ext_vector_type(4))) float f32x4;
typedef __attribute__((ext_vector_type(8))) short s16x8;
typedef __attribute__((ext_vector_type(4))) unsigned short u16x4;
typedef __attribute__((ext_vector_type(8))) unsigned short u16x8;

__device__ __forceinline__ float bf2f(unsigned short u) {
  unsigned int v = ((unsigned int)u) << 16;
  return __builtin_bit_cast(float, v);
}
__device__ __forceinline__ unsigned short f2bf(float f) {
  unsigned int u = __builtin_bit_cast(unsigned int, f);
  u += 0x7fffu + ((u >> 16) & 1u);
  return (unsigned short)(u >> 16);
}

#define GLD16(gp, lp)                                                       \
  __builtin_amdgcn_global_load_lds(                                         \
      (const __attribute__((address_space(1))) void*)(gp),                  \
      (__attribute__((address_space(3))) void*)(lp), 16, 0, 0)

// ---------------------------------------------------------------------------
// Generic bf16 GEMM:  C[m,n] = sum_k A[m,k] * W[n,k]  (+bias, epilogue)
// EPI: 0 = bias -> bf16 ; 1 = bias+relu -> bf16 ; 2 = bias+residual -> f32 ;
//      3 = bias -> f32
// BM=128, BK=64, 4 waves as 2x2, each wave 64 x (BN/2).
// LDS tiles XOR-swizzled (T2): slot ^= (row&7), via pre-swizzled global src.
// Grid: 1-D NX*NY, XCD-bijective swizzle, y (col-block) fastest for A reuse.
// ---------------------------------------------------------------------------
template <int BN, int EPI, int NY>
__global__ __launch_bounds__(256) void gemm_bt(
    const unsigned short* __restrict__ A, const unsigned short* __restrict__ W,
    const float* __restrict__ bias, const float* __restrict__ resid,
    void* __restrict__ Cout, int K, int ldc, int n_valid, int nW) {
  constexpr int BM = 128, BK = 64;
  constexpr int WN = BN / 2;
  constexpr int FM = 4, FN = WN / 16;
  __shared__ unsigned short Alds[BM * BK];
  __shared__ unsigned short Blds[BN * BK];

  const int tid = threadIdx.x, wave = tid >> 6, lane = tid & 63;
  // bijective XCD swizzle (nwg % 8 == 0 for all our grids), then y-fastest
  const int nwg = gridDim.x;
  const int swz = (blockIdx.x & 7) * (nwg >> 3) + (blockIdx.x >> 3);
  const int row0 = (swz / NY) * BM, ncol0 = (swz % NY) * BN;
  const int wr = wave >> 1, wc = wave & 1;
  const int fr = lane & 15, g4 = lane >> 4, ko = g4 * 8;
  const int swr = (fr & 7) << 3;  // read-side XOR (shorts)
  const int l8 = lane >> 3;
  const int lkS = ((lane & 7) ^ l8) * 8;  // pre-swizzled source col (shorts)

  f32x4 acc[FM][FN];
#pragma unroll
  for (int i = 0; i < FM; ++i)
#pragma unroll
    for (int j = 0; j < FN; ++j) acc[i][j] = (f32x4)0.f;

  const int nkt = K / BK;
  for (int kt = 0; kt < nkt; ++kt) {
    __syncthreads();
    // stage A tile [128][64], swizzled source
#pragma unroll
    for (int j = 0; j < 4; ++j) {
      int ci = wave * 4 + j;
      int arow = row0 + ci * 8 + l8;
      const unsigned short* src = A + (size_t)arow * K + kt * BK + lkS;
      GLD16(src, &Alds[ci * 512]);
    }
    // stage B tile [BN][64] (clamped rows for the 51-wide conv)
#pragma unroll
    for (int j = 0; j < BN / 32; ++j) {
      int ci = wave * (BN / 32) + j;
      int brow = ncol0 + ci * 8 + l8;
      if (brow >= nW) brow = nW - 1;
      const unsigned short* src = W + (size_t)brow * K + kt * BK + lkS;
      GLD16(src, &Blds[ci * 512]);
    }
    __syncthreads();
#pragma unroll
    for (int kk = 0; kk < 2; ++kk) {
      s16x8 af[FM], bfr[FN];
#pragma unroll
      for (int i = 0; i < FM; ++i)
        af[i] = *(const s16x8*)&Alds[(wr * 64 + i * 16 + fr) * BK + ((kk * 32 + ko) ^ swr)];
#pragma unroll
      for (int j = 0; j < FN; ++j)
        bfr[j] = *(const s16x8*)&Blds[(wc * WN + j * 16 + fr) * BK + ((kk * 32 + ko) ^ swr)];
#pragma unroll
      for (int i = 0; i < FM; ++i)
#pragma unroll
        for (int j = 0; j < FN; ++j)
          acc[i][j] =
              __builtin_amdgcn_mfma_f32_16x16x32_bf16(af[i], bfr[j], acc[i][j], 0, 0, 0);
    }
  }

  // epilogue: D mapping col=lane&15, row=(lane>>4)*4+r
  const int cr = g4 * 4, cc = lane & 15;
#pragma unroll
  for (int i = 0; i < FM; ++i) {
#pragma unroll
    for (int j = 0; j < FN; ++j) {
      int col = ncol0 + wc * WN + j * 16 + cc;
      if (col >= n_valid) continue;
      float bv = bias[col];
#pragma unroll
      for (int r = 0; r < 4; ++r) {
        int row = row0 + wr * 64 + i * 16 + cr + r;
        float v = acc[i][j][r] + bv;
        if constexpr (EPI == 1) v = fmaxf(v, 0.f);
        size_t idx = (size_t)row * ldc + col;
        if constexpr (EPI == 2) {
          ((float*)Cout)[idx] = v + resid[idx];
        } else if constexpr (EPI == 3) {
          ((float*)Cout)[idx] = v;
        } else {
          ((unsigned short*)Cout)[idx] = f2bf(v);
        }
      }
    }
  }
}

// ---------------------------------------------------------------------------
// LayerNorm: unbiased var (D-1), out = a*(x-mean)/(sqrt(var)+1e-6)+b -> bf16
// ---------------------------------------------------------------------------
__global__ __launch_bounds__(256) void ln_kernel(const float* __restrict__ x,
                                                 const float* __restrict__ a,
                                                 const float* __restrict__ b,
                                                 unsigned short* __restrict__ out) {
  const int wave = threadIdx.x >> 6, lane = threadIdx.x & 63;
  const size_t row = (size_t)blockIdx.x * 4 + wave;
  const float* xr = x + row * 256;
  f32x4 v = *(const f32x4*)(xr + lane * 4);
  float s = v[0] + v[1] + v[2] + v[3];
#pragma unroll
  for (int off = 32; off >= 1; off >>= 1) s += __shfl_xor(s, off);
  float mean = s * (1.f / 256.f);
  f32x4 d = v - mean;
  float sq = d[0] * d[0] + d[1] * d[1] + d[2] * d[2] + d[3] * d[3];
#pragma unroll
  for (int off = 32; off >= 1; off >>= 1) sq += __shfl_xor(sq, off);
  float var = sq * (1.f / 255.f);
  float scl = 1.f / (sqrtf(var) + 1e-6f);
  f32x4 av = *(const f32x4*)(a + lane * 4);
  f32x4 bv = *(const f32x4*)(b + lane * 4);
  u16x4 ob;
#pragma unroll
  for (int j = 0; j < 4; ++j) ob[j] = f2bf(av[j] * d[j] * scl + bv[j]);
  *(u16x4*)(out + row * 256 + lane * 4) = ob;
}

// ---------------------------------------------------------------------------
// MFMA strided sparse attention. 1 wave = 1 stream (b,h,m); 4 waves/block.
// ---------------------------------------------------------------------------
__global__ __launch_bounds__(256) void attn_mfma(const unsigned short* __restrict__ qkv,
                                                 unsigned short* __restrict__ o) {
  constexpr int LS = 40;  // LDS row stride in shorts
  const int wave = threadIdx.x >> 6, lane = threadIdx.x & 63;
  const int sid = blockIdx.x * 4 + wave;
  const int m = sid % 3, hh = (sid / 3) & 7, b = sid / 24;
  __shared__ unsigned short VtS[4][32 * LS];
  __shared__ unsigned short PlS[4][32 * LS];
  unsigned short* vt = VtS[wave];
  unsigned short* pl = PlS[wave];

  const unsigned short* base = qkv + (size_t)b * 81 * 768 + (size_t)m * 768 + hh * 32;
  const int fr = lane & 15;        // fragment row index (q / kix / d)
  const int ko = (lane >> 4) * 8;  // k-dim slice start
  const int g4 = lane >> 4;

  // Q and K fragments from global (row-clamped; dup of row 26 is masked later)
  s16x8 qf[2], kf[2];
#pragma unroll
  for (int i = 0; i < 2; ++i) {
    int g = fr + 16 * i;
    if (g > 26) g = 26;
    const unsigned short* qp = base + (size_t)g * 2304 + ko;
    qf[i] = *(const s16x8*)qp;
    kf[i] = *(const s16x8*)(qp + 256);
  }

  // Stage V transposed: vt[d][k] = V[k][d], zero pad k>=27
#pragma unroll
  for (int it = 0; it < 2; ++it) {
    int slot = it * 64 + lane;
    int g = slot >> 2, s = slot & 3;
    if (g < 27) {
      u16x8 v = *(const u16x8*)(base + (size_t)g * 2304 + 512 + s * 8);
#pragma unroll
      for (int j = 0; j < 8; ++j) vt[(s * 8 + j) * LS + g] = v[j];
    } else {
#pragma unroll
      for (int j = 0; j < 8; ++j) vt[(s * 8 + j) * LS + g] = 0;
    }
  }

  // S = Q K^T (padded 32x32), quadrants [i][j]
  f32x4 sacc[2][2];
#pragma unroll
  for (int i = 0; i < 2; ++i)
#pragma unroll
    for (int j = 0; j < 2; ++j) sacc[i][j] = (f32x4)0.f;
#pragma unroll
  for (int i = 0; i < 2; ++i)
#pragma unroll
    for (int j = 0; j < 2; ++j)
      sacc[i][j] = __builtin_amdgcn_mfma_f32_16x16x32_bf16(qf[i], kf[j], sacc[i][j], 0, 0, 0);

  // softmax over k (cols): row = i*16+4*g4+r, col = j*16+fr; valid col<27
  const float scale = 0.17677669529663687f;  // 1/sqrt(32)
  const bool v1 = fr < 11;
#pragma unroll
  for (int i = 0; i < 2; ++i) {
#pragma unroll
    for (int r = 0; r < 4; ++r) {
      float a0 = sacc[i][0][r] * scale;
      float a1 = v1 ? sacc[i][1][r] * scale : -3.0e38f;
      float mx = fmaxf(a0, a1);
#pragma unroll
      for (int off = 1; off <= 8; off <<= 1) mx = fmaxf(mx, __shfl_xor(mx, off));
      float e0 = __expf(a0 - mx);
      float e1 = v1 ? __expf(a1 - mx) : 0.f;
      float sm = e0 + e1;
#pragma unroll
      for (int off = 1; off <= 8; off <<= 1) sm += __shfl_xor(sm, off);
      float inv = 1.f / sm;
      int row = i * 16 + 4 * g4 + r;
      pl[row * LS + fr] = f2bf(e0 * inv);
      pl[row * LS + 16 + fr] = f2bf(e1 * inv);
    }
  }
  __syncthreads();  // P + Vt visible

  // P A-frags and V^T B-frags
  s16x8 pf[2], vf[2];
#pragma unroll
  for (int i = 0; i < 2; ++i) pf[i] = *(const s16x8*)&pl[(fr + 16 * i) * LS + ko];
#pragma unroll
  for (int j = 0; j < 2; ++j) vf[j] = *(const s16x8*)&vt[(fr + 16 * j) * LS + ko];

  f32x4 oacc[2][2];
#pragma unroll
  for (int i = 0; i < 2; ++i)
#pragma unroll
    for (int j = 0; j < 2; ++j) oacc[i][j] = (f32x4)0.f;
#pragma unroll
  for (int i = 0; i < 2; ++i)
#pragma unroll
    for (int j = 0; j < 2; ++j)
      oacc[i][j] = __builtin_amdgcn_mfma_f32_16x16x32_bf16(pf[i], vf[j], oacc[i][j], 0, 0, 0);

  __syncthreads();  // vf/pf reads drained; safe to overwrite vt with O
#pragma unroll
  for (int i = 0; i < 2; ++i)
#pragma unroll
    for (int j = 0; j < 2; ++j)
#pragma unroll
      for (int r = 0; r < 4; ++r)
        vt[(i * 16 + 4 * g4 + r) * LS + j * 16 + fr] = f2bf(oacc[i][j][r]);
  __syncthreads();

  // coalesced store: row g (<27), 16B per lane
#pragma unroll
  for (int it = 0; it < 2; ++it) {
    int slot = it * 64 + lane;
    int g = slot >> 2, s = slot & 3;
    if (g < 27) {
      u16x8 v = *(const u16x8*)&vt[g * LS + s * 8];
      *(u16x8*)(o + (size_t)(b * 81 + m + 3 * g) * 256 + hh * 32 + s * 8) = v;
    }
  }
}

// x + pos_emb (pos broadcast over batch), float4 per thread
__global__ __launch_bounds__(256) void addpos_kernel(const f32x4* __restrict__ x,
                                                     const f32x4* __restrict__ pos,
                                                     f32x4* __restrict__ out) {
  int i = blockIdx.x * 256 + threadIdx.x;  // 5,308,416 float4s
  out[i] = x[i] + pos[i % 5184];
}

// eval BatchNorm (mean0/var1) fused cast: xn = x/sqrt(1+1e-5)*g + b -> bf16
__global__ __launch_bounds__(256) void bn_kernel(const float* __restrict__ x,
                                                 const float* __restrict__ g,
                                                 const float* __restrict__ bb,
                                                 unsigned short* __restrict__ out) {
  int i = blockIdx.x * 256 + threadIdx.x;  // float4 index
  f32x4 v = ((const f32x4*)x)[i];
  int c = (i << 2) & 255;
  f32x4 gv = *(const f32x4*)(g + c);
  f32x4 bv = *(const f32x4*)(bb + c);
  const float is = 0.9999950000374997f;  // 1/sqrt(1.00001)
  u16x4 o;
#pragma unroll
  for (int j = 0; j < 4; ++j) o[j] = f2bf(v[j] * is * gv[j] + bv[j]);
  ((u16x4*)out)[i] = o;
}

__global__ __launch_bounds__(256) void cvt_kernel(const f32x4* __restrict__ src,
                                                  u16x4* __restrict__ dst, int n4) {
  int i = blockIdx.x * 256 + threadIdx.x;
  if (i < n4) {
    f32x4 v = src[i];
    u16x4 o;
#pragma unroll
    for (int j = 0; j < 4; ++j) o[j] = f2bf(v[j]);
    dst[i] = o;
  }
}

// pack Wq|Wk|Wv -> wqkv3 bf16 [3][768][256]
__global__ __launch_bounds__(256) void qkvpack_kernel(const float* __restrict__ Wq,
                                                      const float* __restrict__ Wk,
                                                      const float* __restrict__ Wv,
                                                      u16x4* __restrict__ dst) {
  int i4 = blockIdx.x * 256 + threadIdx.x;  // 147456 total
  int e = i4 * 4;
  int l = e / 196608;
  int r = (e / 256) % 768;
  int c = e & 255;
  const float* src;
  if (r < 256) src = Wq + (size_t)l * 65536 + r * 256 + c;
  else if (r < 512) src = Wk + (size_t)l * 65536 + (r - 256) * 256 + c;
  else src = Wv + (size_t)l * 65536 + (r - 512) * 256 + c;
  f32x4 v = *(const f32x4*)src;
  u16x4 o;
#pragma unroll
  for (int j = 0; j < 4; ++j) o[j] = f2bf(v[j]);
  dst[i4] = o;
}

__global__ __launch_bounds__(256) void biaspack_kernel(const float* __restrict__ bq,
                                                       const float* __restrict__ bk,
                                                       const float* __restrict__ bv,
                                                       float* __restrict__ dst) {
  int i = blockIdx.x * 256 + threadIdx.x;
  if (i >= 2304) return;
  int l = i / 768, r = i % 768;
  float v = (r < 256) ? bq[l * 256 + r] : (r < 512) ? bk[l * 256 + r - 256]
                                                    : bv[l * 256 + r - 512];
  dst[i] = v;
}

extern "C" void kernel_launch(void* const* d_in, const int* in_sizes, int n_in,
                              void* d_out, int out_size, void* d_ws, size_t ws_size,
                              hipStream_t stream) {
  const float* x      = (const float*)d_in[0];
  const float* pos    = (const float*)d_in[1];
  const float* ln1_a  = (const float*)d_in[2];
  const float* ln1_b  = (const float*)d_in[3];
  const float* Wq     = (const float*)d_in[4];
  const float* bq     = (const float*)d_in[5];
  const float* Wk     = (const float*)d_in[6];
  const float* bk     = (const float*)d_in[7];
  const float* Wv     = (const float*)d_in[8];
  const float* bv     = (const float*)d_in[9];
  const float* Wo     = (const float*)d_in[10];
  const float* bo     = (const float*)d_in[11];
  const float* ln2_a  = (const float*)d_in[12];
  const float* ln2_b  = (const float*)d_in[13];
  const float* W1     = (const float*)d_in[14];
  const float* b1     = (const float*)d_in[15];
  const float* W2     = (const float*)d_in[16];
  const float* b2     = (const float*)d_in[17];
  const float* bn_g   = (const float*)d_in[18];
  const float* bn_b   = (const float*)d_in[19];
  const float* conv_w = (const float*)d_in[20];
  const float* conv_b = (const float*)d_in[21];

  char* ws = (char*)d_ws;
  float* xbuf = (float*)ws;
  unsigned short* bufA = (unsigned short*)(ws + 84934656);
  unsigned short* bufB = (unsigned short*)(ws + 127401984);
  unsigned short* wqkv3 = (unsigned short*)(ws + 254803968);
  unsigned short* wo3 = wqkv3 + 589824;
  unsigned short* w13 = wo3 + 196608;
  unsigned short* w23 = w13 + 393216;
  unsigned short* cw  = w23 + 393216;
  float* qkvb3 = (float*)(ws + 254803968 + 3171840);

  auto cvt = [&](const float* s, unsigned short* d, int n) {
    int n4 = n / 4;
    cvt_kernel<<<(n4 + 255) / 256, 256, 0, stream>>>((const f32x4*)s, (u16x4*)d, n4);
  };
  qkvpack_kernel<<<576, 256, 0, stream>>>(Wq, Wk, Wv, (u16x4*)wqkv3);
  biaspack_kernel<<<9, 256, 0, stream>>>(bq, bk, bv, qkvb3);
  cvt(Wo, wo3, 196608);
  cvt(W1, w13, 393216);
  cvt(W2, w23, 393216);
  cvt(conv_w, cw, 13056);

  addpos_kernel<<<20736, 256, 0, stream>>>((const f32x4*)x, (const f32x4*)pos, (f32x4*)xbuf);

  for (int l = 0; l < 3; ++l) {
    ln_kernel<<<20736, 256, 0, stream>>>(xbuf, ln1_a + l * 256, ln1_b + l * 256, bufA);
    // fused QKV: one GEMM into [BT,768]
    gemm_bt<128, 0, 6><<<3888, 256, 0, stream>>>(bufA, wqkv3 + l * 196608,
                                                 qkvb3 + l * 768, nullptr,
                                                 (void*)bufB, 256, 768, 768, 768);
    attn_mfma<<<6144, 256, 0, stream>>>(bufB, bufA);
    gemm_bt<128, 2, 2><<<1296, 256, 0, stream>>>(bufA, wo3 + l * 65536, bo + l * 256,
                                                 xbuf, (void*)xbuf, 256, 256, 256, 256);
    ln_kernel<<<20736, 256, 0, stream>>>(xbuf, ln2_a + l * 256, ln2_b + l * 256, bufA);
    gemm_bt<128, 1, 4><<<2592, 256, 0, stream>>>(bufA, w13 + l * 131072, b1 + l * 512,
                                                 nullptr, (void*)bufB, 256, 512, 512, 512);
    gemm_bt<128, 2, 2><<<1296, 256, 0, stream>>>(bufB, w23 + l * 131072, b2 + l * 256,
                                                 xbuf, (void*)xbuf, 512, 256, 256, 256);
  }
  bn_kernel<<<20736, 256, 0, stream>>>(xbuf, bn_g, bn_b, bufA);
  gemm_bt<64, 3, 1><<<648, 256, 0, stream>>>(bufA, cw, conv_b, nullptr, d_out, 256, 51,
                                             51, 51);
}